// Round 5
// baseline (572.529 us; speedup 1.0000x reference)
//
#include <hip/hip_runtime.h>
#include <hip/hip_bf16.h>

// INT8 dynamic-quant GEMM: out = (x_int8 @ w_int8^T) * (x_scales * w_scales^T)
// x: [M,K] f32, w: [N,K] f32, out: [M,N] f32.  M=8192, K=4096, N=11008.

#define QEPS 1e-5f

using int4v = __attribute__((ext_vector_type(4))) int;

typedef __attribute__((address_space(3))) signed char lds_i8_t;
typedef __attribute__((address_space(1))) const signed char glb_i8_t;

// ---------------- per-row absmax quantize (K = 4096 fixed) ----------------
__global__ __launch_bounds__(256) void quant_rows_k(const float* __restrict__ in,
                                                    signed char* __restrict__ out8,
                                                    float* __restrict__ scales) {
    const int K = 4096;
    const int row = blockIdx.x;
    const int t = threadIdx.x;
    const float4* in4 = (const float4*)(in + (size_t)row * K);
    float4 v[4];
    float amax = 0.f;
#pragma unroll
    for (int j = 0; j < 4; ++j) {
        v[j] = in4[t + 256 * j];
        amax = fmaxf(amax, fmaxf(fmaxf(fabsf(v[j].x), fabsf(v[j].y)),
                                 fmaxf(fabsf(v[j].z), fabsf(v[j].w))));
    }
#pragma unroll
    for (int off = 32; off > 0; off >>= 1)
        amax = fmaxf(amax, __shfl_xor(amax, off));
    __shared__ float wmax[4];
    if ((t & 63) == 0) wmax[t >> 6] = amax;
    __syncthreads();
    amax = fmaxf(fmaxf(wmax[0], wmax[1]), fmaxf(wmax[2], wmax[3]));
    const float scale = fmaxf(amax, QEPS) / 127.0f;
    if (t == 0) scales[row] = scale;
    char4* o4 = (char4*)(out8 + (size_t)row * K);
#pragma unroll
    for (int j = 0; j < 4; ++j) {
        char4 q;
        q.x = (signed char)(int)rintf(v[j].x / scale);  // rintf = round-half-even = jnp.round
        q.y = (signed char)(int)rintf(v[j].y / scale);
        q.z = (signed char)(int)rintf(v[j].z / scale);
        q.w = (signed char)(int)rintf(v[j].w / scale);
        o4[t + 256 * j] = q;
    }
}

// ---- int8 GEMM, 256x256 tile, BK=64, quad-buffered, paired K-steps ----
// LDS rows are 64 B with XOR swizzle: lds[row][c] = global[row][c ^ ((row>>1)&3)<<4]
// -> each 16-lane fragment read group spreads over 2 banksets x 4 slots = 2-way (free).
// Swizzle permutes 16B units WITHIN each 64B row -> staging global sources stay
// fully coalesced; global_load_lds dest stays linear (required).
// Schedule per iteration (2 K-steps):
//   compute(buf[u]); compute(buf[u+1]);   <- contiguous, no barrier: ds_read/MFMA overlap
//   barrier; STAGE(u+4 -> buf[u&3]); STAGE(u+5 -> buf[(u+1)&3]);
//   vmcnt(8)  <- waits only for loads issued TWO iterations ago (~5000 cyc lead, no stall)
//   barrier
__global__ __launch_bounds__(512, 2) void gemm_i8_q4(const signed char* __restrict__ A,
                                                     const signed char* __restrict__ B,
                                                     const float* __restrict__ xs,
                                                     const float* __restrict__ wsc,
                                                     float* __restrict__ C) {
    constexpr int K = 4096;
    constexpr int N = 11008;
    constexpr int BK = 64;
    constexpr int NT = K / BK;        // 64
    constexpr int TILE = 256 * BK;    // 16 KB per matrix per buffer

    __shared__ __align__(16) signed char lsA[4][TILE];  // 64 KB
    __shared__ __align__(16) signed char lsB[4][TILE];  // 64 KB

    const int t = threadIdx.x;
    const int lane = t & 63;
    const int wid = t >> 6;
    const int wr = wid >> 2;   // 0..1 -> 128 output rows
    const int wc = wid & 3;    // 0..3 -> 64 output cols

    // XCD-aware swizzle: grid 1376 = 8 XCDs x 172 (bijective)
    const int wg = (blockIdx.x & 7) * ((int)gridDim.x >> 3) + ((int)blockIdx.x >> 3);
    const int by = wg / 43;
    const int bx = wg - by * 43;
    const int brow = by * 256;
    const int bcol = bx * 256;

    // staging: chunk = i*512 + t (i=0,1); row = chunk>>2, slot = chunk&3
    // pre-swizzled source col; (row>>1)&3 is identical for i=0 and i=1 (+128 rows)
    const int srow = t >> 2;                                   // 0..127 (+128 for i=1)
    const int scol = ((t & 3) * 16) ^ ((((t >> 3)) & 3) << 4); // slot*16 ^ ((row>>1)&3)<<4
    const signed char* aSrc = A + (size_t)(brow + srow) * K + scol;
    const signed char* bSrc = B + (size_t)(bcol + srow) * K + scol;

    // fragment geometry (mfma_i32_16x16x64_i8): row = lane&15, k-grp = (lane>>4)*16
    const int arow0 = wr * 128 + (lane & 15);
    const int bcol0 = wc * 64 + (lane & 15);
    // read col with matching XOR; (row>>1)&3 == ((lane&15)>>1)&3 for all frag rows
    const int colf = ((lane >> 4) * 16) ^ ((((lane & 15) >> 1) & 3) << 4);

    int4v acc[8][4];
#pragma unroll
    for (int m = 0; m < 8; ++m)
#pragma unroll
        for (int n = 0; n < 4; ++n) acc[m][n] = (int4v){0, 0, 0, 0};

#define STAGE(BUF, KT)                                                                     \
    do {                                                                                   \
        const size_t ko = (size_t)(KT)*BK;                                                 \
        __builtin_amdgcn_global_load_lds((glb_i8_t*)(aSrc + ko),                           \
                                         (lds_i8_t*)(&lsA[BUF][0] + t * 16), 16, 0, 0);    \
        __builtin_amdgcn_global_load_lds((glb_i8_t*)(aSrc + (size_t)128 * K + ko),         \
                                         (lds_i8_t*)(&lsA[BUF][8192] + t * 16), 16, 0, 0); \
        __builtin_amdgcn_global_load_lds((glb_i8_t*)(bSrc + ko),                           \
                                         (lds_i8_t*)(&lsB[BUF][0] + t * 16), 16, 0, 0);    \
        __builtin_amdgcn_global_load_lds((glb_i8_t*)(bSrc + (size_t)128 * K + ko),         \
                                         (lds_i8_t*)(&lsB[BUF][8192] + t * 16), 16, 0, 0); \
    } while (0)

    auto compute_tile = [&](const signed char* LA, const signed char* LB) {
        int4v bf[4];
#pragma unroll
        for (int n = 0; n < 4; ++n)
            bf[n] = *(const int4v*)(LB + (bcol0 + n * 16) * 64 + colf);
        int4v af[8];
#pragma unroll
        for (int mi = 0; mi < 8; ++mi)
            af[mi] = *(const int4v*)(LA + (arow0 + mi * 16) * 64 + colf);
        __builtin_amdgcn_s_setprio(1);
#pragma unroll
        for (int mi = 0; mi < 8; ++mi)
#pragma unroll
            for (int n = 0; n < 4; ++n)
                acc[mi][n] = __builtin_amdgcn_mfma_i32_16x16x64_i8(af[mi], bf[n],
                                                                   acc[mi][n], 0, 0, 0);
        __builtin_amdgcn_s_setprio(0);
    };

    // prologue: stage tiles 0..3 into bufs 0..3; wait for 0,1 (allow 2,3 in flight)
    STAGE(0, 0);
    STAGE(1, 1);
    STAGE(2, 2);
    STAGE(3, 3);
    asm volatile("s_waitcnt vmcnt(8)" ::: "memory");
    __builtin_amdgcn_s_barrier();

#pragma unroll 1
    for (int u = 0; u < NT; u += 2) {
        compute_tile(&lsA[u & 3][0], &lsB[u & 3][0]);
        compute_tile(&lsA[(u + 1) & 3][0], &lsB[(u + 1) & 3][0]);
        __builtin_amdgcn_s_barrier();   // all waves done reading bufs u, u+1
        STAGE(u & 3, (u + 4) & (NT - 1));         // wrapped tail stages: redundant-but-safe
        STAGE((u + 1) & 3, (u + 5) & (NT - 1));
        asm volatile("s_waitcnt vmcnt(8)" ::: "memory");  // tiles u+2,u+3 landed; u+4,u+5 in flight
        __builtin_amdgcn_s_barrier();
    }
#undef STAGE

    // epilogue: C/D frag layout col=lane&15, row=(lane>>4)*4+reg
    const int rgrp = (lane >> 4) * 4;
    float wsv[4];
#pragma unroll
    for (int n = 0; n < 4; ++n) wsv[n] = wsc[bcol + wc * 64 + n * 16 + (lane & 15)];
#pragma unroll
    for (int m = 0; m < 8; ++m) {
#pragma unroll
        for (int r = 0; r < 4; ++r) {
            const int row = brow + wr * 128 + m * 16 + rgrp + r;
            const float xsv = xs[row];
            const size_t base = (size_t)row * N + bcol + wc * 64 + (lane & 15);
#pragma unroll
            for (int n = 0; n < 4; ++n)
                C[base + n * 16] = (float)acc[m][n][r] * (xsv * wsv[n]);
        }
    }
}

extern "C" void kernel_launch(void* const* d_in, const int* in_sizes, int n_in,
                              void* d_out, int out_size, void* d_ws, size_t ws_size,
                              hipStream_t stream) {
    const float* x = (const float*)d_in[0];
    const float* w = (const float*)d_in[1];
    float* out = (float*)d_out;

    const int K = 4096;
    const int M = in_sizes[0] / K;   // 8192
    const int N = in_sizes[1] / K;   // 11008

    signed char* x8 = (signed char*)d_ws;
    signed char* w8 = x8 + (size_t)M * K;
    float* xscales = (float*)(w8 + (size_t)N * K);
    float* wscales = xscales + M;

    quant_rows_k<<<M, 256, 0, stream>>>(x, x8, xscales);
    quant_rows_k<<<N, 256, 0, stream>>>(w, w8, wscales);
    const int nwg = (M / 256) * (N / 256);   // 32*43 = 1376 = 8*172
    gemm_i8_q4<<<nwg, 512, 0, stream>>>(x8, w8, xscales, wscales, out);
}

// Round 6
// 498.278 us; speedup vs baseline: 1.1490x; 1.1490x over previous
//
#include <hip/hip_runtime.h>
#include <hip/hip_bf16.h>

// INT8 dynamic-quant GEMM: out = (x_int8 @ w_int8^T) * (x_scales * w_scales^T)
// x: [M,K] f32, w: [N,K] f32, out: [M,N] f32.  M=8192, K=4096, N=11008.

#define QEPS 1e-5f

using int4v = __attribute__((ext_vector_type(4))) int;

typedef __attribute__((address_space(3))) signed char lds_i8_t;
typedef __attribute__((address_space(1))) const signed char glb_i8_t;

// ---------------- per-row absmax quantize (K = 4096 fixed) ----------------
__global__ __launch_bounds__(256) void quant_rows_k(const float* __restrict__ in,
                                                    signed char* __restrict__ out8,
                                                    float* __restrict__ scales) {
    const int K = 4096;
    const int row = blockIdx.x;
    const int t = threadIdx.x;
    const float4* in4 = (const float4*)(in + (size_t)row * K);
    float4 v[4];
    float amax = 0.f;
#pragma unroll
    for (int j = 0; j < 4; ++j) {
        v[j] = in4[t + 256 * j];
        amax = fmaxf(amax, fmaxf(fmaxf(fabsf(v[j].x), fabsf(v[j].y)),
                                 fmaxf(fabsf(v[j].z), fabsf(v[j].w))));
    }
#pragma unroll
    for (int off = 32; off > 0; off >>= 1)
        amax = fmaxf(amax, __shfl_xor(amax, off));
    __shared__ float wmax[4];
    if ((t & 63) == 0) wmax[t >> 6] = amax;
    __syncthreads();
    amax = fmaxf(fmaxf(wmax[0], wmax[1]), fmaxf(wmax[2], wmax[3]));
    const float scale = fmaxf(amax, QEPS) / 127.0f;
    if (t == 0) scales[row] = scale;
    char4* o4 = (char4*)(out8 + (size_t)row * K);
#pragma unroll
    for (int j = 0; j < 4; ++j) {
        char4 q;
        q.x = (signed char)(int)rintf(v[j].x / scale);  // rintf = round-half-even = jnp.round
        q.y = (signed char)(int)rintf(v[j].y / scale);
        q.z = (signed char)(int)rintf(v[j].z / scale);
        q.w = (signed char)(int)rintf(v[j].w / scale);
        o4[t + 256 * j] = q;
    }
}

// ---- int8 GEMM, 256x256, BK=128, TRUE 8-phase with round-2 staging ----
// LDS layout/staging identical to round 2 (measured best): row-major 128 B
// rows, XOR swizzle col^=(row&7)<<4 via pre-swizzled global source; each
// stage load covers 64 rows x 128 B (8-lane x 128 B contiguous transactions).
// Per K-tile u: 4 phases = C-quadrants (ks,mh): P0(0,0) P1(1,0) P2(0,1)
// P3(1,1); 16 MFMA each. Each phase stages one PAIR of next tile's loads in
// consumption order: P0:{B0,B1} P1:{B2,B3} P2:{A0,A2} P3:{A1,A3}.
// Counted gates: vmcnt(4) end-P1 (waits prev A1,A3; needed at P2),
// vmcnt(2) end-P3 (waits B0-3,A0,A2 of next tile; leaves A1,A3 in flight).
// Never vmcnt(0) in the loop (T4). Explicit lgkmcnt(0)+sched_barrier after
// each barrier (rule 18); setprio around MFMA (T5); XCD swizzle (T1).
__global__ __launch_bounds__(512, 2) void gemm_i8_8p(const signed char* __restrict__ A,
                                                     const signed char* __restrict__ B,
                                                     const float* __restrict__ xs,
                                                     const float* __restrict__ wsc,
                                                     float* __restrict__ C) {
    constexpr int K = 4096;
    constexpr int N = 11008;
    constexpr int BK = 128;
    constexpr int NT = 32;
    constexpr int TILE = 256 * 128;  // 32 KB

    __shared__ __align__(16) signed char lsA[2][TILE];
    __shared__ __align__(16) signed char lsB[2][TILE];

    const int t = threadIdx.x;
    const int lane = t & 63;
    const int wid = t >> 6;
    const int wr = wid >> 2;   // 0..1 -> 128 output rows
    const int wc = wid & 3;    // 0..3 -> 64 output cols

    // XCD-aware swizzle: grid 1376 = 8 XCDs x 172 (bijective)
    const int wg = (blockIdx.x & 7) * ((int)gridDim.x >> 3) + ((int)blockIdx.x >> 3);
    const int by = wg / 43;
    const int bx = wg - by * 43;
    const int brow = by * 256;
    const int bcol = bx * 256;

    // staging: chunk = t; row = t>>3 (+64 per j), slot = t&7; pre-swizzled src col
    const int srow = t >> 3;
    const int scol = ((t & 7) * 16) ^ ((srow & 7) << 4);
    const signed char* aptr = A + (size_t)(brow + srow) * K + scol;
    const signed char* bptr = B + (size_t)(bcol + srow) * K + scol;

    // fragment geometry (mfma_i32_16x16x64_i8): row = lane&15, k-grp = (lane>>4)*16
    const int arow0 = wr * 128 + (lane & 15);
    const int bcol0 = wc * 64 + (lane & 15);
    const int kgrp = (lane >> 4) * 16;
    const int sw = (lane & 7) << 4;

    int4v acc[8][4];
#pragma unroll
    for (int m = 0; m < 8; ++m)
#pragma unroll
        for (int n = 0; n < 4; ++n) acc[m][n] = (int4v){0, 0, 0, 0};

#define LDA_(J, KOFF, SB)                                                                  \
    __builtin_amdgcn_global_load_lds((glb_i8_t*)(aptr + (size_t)((J)*64) * K + (KOFF)),    \
                                     (lds_i8_t*)(&lsA[SB][0] + ((J)*512 + t) * 16), 16, 0, 0)
#define LDB_(J, KOFF, SB)                                                                  \
    __builtin_amdgcn_global_load_lds((glb_i8_t*)(bptr + (size_t)((J)*64) * K + (KOFF)),    \
                                     (lds_i8_t*)(&lsB[SB][0] + ((J)*512 + t) * 16), 16, 0, 0)

    // prologue: tile 0 into buf0, consumption order B0..B3, A0, A2, A1, A3
    LDB_(0, 0, 0); LDB_(1, 0, 0); LDB_(2, 0, 0); LDB_(3, 0, 0);
    LDA_(0, 0, 0); LDA_(2, 0, 0); LDA_(1, 0, 0); LDA_(3, 0, 0);
    asm volatile("s_waitcnt vmcnt(2)" ::: "memory");  // B0-3, A0, A2 landed; A1, A3 in flight
    __builtin_amdgcn_s_barrier();

    int4v bf0[4], bf1[4];

#define MFMA16(MH, BF)                                                                     \
    __builtin_amdgcn_s_setprio(1);                                                         \
    _Pragma("unroll") for (int mi = 0; mi < 4; ++mi)                                       \
        _Pragma("unroll") for (int n = 0; n < 4; ++n)                                      \
            acc[(MH)*4 + mi][n] = __builtin_amdgcn_mfma_i32_16x16x64_i8(                   \
                af[mi], BF[n], acc[(MH)*4 + mi][n], 0, 0, 0);                              \
    __builtin_amdgcn_s_setprio(0);                                                         \
    __builtin_amdgcn_s_barrier();

#define BAR_LGKM()                                                                         \
    __builtin_amdgcn_s_barrier();                                                          \
    asm volatile("s_waitcnt lgkmcnt(0)" ::: "memory");                                     \
    __builtin_amdgcn_sched_barrier(0);

#pragma unroll 1
    for (int u = 0; u < NT; ++u) {
        const int cb = u & 1, sb = cb ^ 1;
        const signed char* cA = &lsA[cb][0];
        const signed char* cB = &lsB[cb][0];
        const size_t koff = (size_t)((u + 1) & (NT - 1)) * BK;  // wrapped tail: redundant restage
        int4v af[4];

        // P0: (ks0, mh0); stage B0,B1
#pragma unroll
        for (int n = 0; n < 4; ++n)
            bf0[n] = *(const int4v*)(cB + (bcol0 + n * 16) * 128 + (kgrp ^ sw));
#pragma unroll
        for (int mi = 0; mi < 4; ++mi)
            af[mi] = *(const int4v*)(cA + (arow0 + mi * 16) * 128 + (kgrp ^ sw));
        LDB_(0, koff, sb); LDB_(1, koff, sb);
        BAR_LGKM();
        MFMA16(0, bf0);

        // P1: (ks1, mh0); stage B2,B3; gate vmcnt(4) -> waits prev A1,A3
#pragma unroll
        for (int n = 0; n < 4; ++n)
            bf1[n] = *(const int4v*)(cB + (bcol0 + n * 16) * 128 + ((64 + kgrp) ^ sw));
#pragma unroll
        for (int mi = 0; mi < 4; ++mi)
            af[mi] = *(const int4v*)(cA + (arow0 + mi * 16) * 128 + ((64 + kgrp) ^ sw));
        LDB_(2, koff, sb); LDB_(3, koff, sb);
        asm volatile("s_waitcnt vmcnt(4)" ::: "memory");
        BAR_LGKM();
        MFMA16(0, bf1);

        // P2: (ks0, mh1); stage A0,A2   (bf0 reused from registers)
#pragma unroll
        for (int mi = 0; mi < 4; ++mi)
            af[mi] = *(const int4v*)(cA + (arow0 + 64 + mi * 16) * 128 + (kgrp ^ sw));
        LDA_(0, koff, sb); LDA_(2, koff, sb);
        BAR_LGKM();
        MFMA16(1, bf0);

        // P3: (ks1, mh1); stage A1,A3; gate vmcnt(2) -> next tile's B0-3,A0,A2 landed
#pragma unroll
        for (int mi = 0; mi < 4; ++mi)
            af[mi] = *(const int4v*)(cA + (arow0 + 64 + mi * 16) * 128 + ((64 + kgrp) ^ sw));
        LDA_(1, koff, sb); LDA_(3, koff, sb);
        asm volatile("s_waitcnt vmcnt(2)" ::: "memory");
        BAR_LGKM();
        MFMA16(1, bf1);
    }
#undef MFMA16
#undef BAR_LGKM
#undef LDA_
#undef LDB_

    // drain remaining staged loads before LDS goes out of scope
    asm volatile("s_waitcnt vmcnt(0)" ::: "memory");

    // epilogue: C/D frag layout col=lane&15, row=(lane>>4)*4+reg
    const int rgrp = (lane >> 4) * 4;
    float wsv[4];
#pragma unroll
    for (int n = 0; n < 4; ++n) wsv[n] = wsc[bcol + wc * 64 + n * 16 + (lane & 15)];
#pragma unroll
    for (int m = 0; m < 8; ++m) {
#pragma unroll
        for (int r = 0; r < 4; ++r) {
            const int row = brow + wr * 128 + m * 16 + rgrp + r;
            const float xsv = xs[row];
            const size_t base = (size_t)row * N + bcol + wc * 64 + (lane & 15);
#pragma unroll
            for (int n = 0; n < 4; ++n)
                C[base + n * 16] = (float)acc[m][n][r] * (xsv * wsv[n]);
        }
    }
}

extern "C" void kernel_launch(void* const* d_in, const int* in_sizes, int n_in,
                              void* d_out, int out_size, void* d_ws, size_t ws_size,
                              hipStream_t stream) {
    const float* x = (const float*)d_in[0];
    const float* w = (const float*)d_in[1];
    float* out = (float*)d_out;

    const int K = 4096;
    const int M = in_sizes[0] / K;   // 8192
    const int N = in_sizes[1] / K;   // 11008

    signed char* x8 = (signed char*)d_ws;
    signed char* w8 = x8 + (size_t)M * K;
    float* xscales = (float*)(w8 + (size_t)N * K);
    float* wscales = xscales + M;

    quant_rows_k<<<M, 256, 0, stream>>>(x, x8, xscales);
    quant_rows_k<<<N, 256, 0, stream>>>(w, w8, wscales);
    const int nwg = (M / 256) * (N / 256);   // 32*43 = 1376 = 8*172
    gemm_i8_8p<<<nwg, 512, 0, stream>>>(x8, w8, xscales, wscales, out);
}